// Round 3
// baseline (118.257 us; speedup 1.0000x reference)
//
#include <hip/hip_runtime.h>
#include <hip/hip_bf16.h>
#include <stdint.h>

typedef __attribute__((ext_vector_type(8))) short short8;
typedef __attribute__((ext_vector_type(4))) float f32x4;
typedef __attribute__((ext_vector_type(4))) unsigned short u16x4;

__device__ __forceinline__ float bf2f(unsigned short u) {
  union { unsigned int u; float f; } x; x.u = ((unsigned int)u) << 16; return x.f;
}
__device__ __forceinline__ unsigned short f2bf(float f) {
  union { float f; unsigned int u; } x; x.f = f;
  unsigned int u = x.u;
  return (unsigned short)((u + 0x7fffu + ((u >> 16) & 1u)) >> 16);
}

__device__ __forceinline__ void gload_lds16(const void* g, void* l) {
  __builtin_amdgcn_global_load_lds(
      (const __attribute__((address_space(1))) void*)g,
      (__attribute__((address_space(3))) void*)l, 16, 0, 0);
}

// ---------------- fp32 -> bf16 converts ----------------
__global__ void cvt4(const float* __restrict__ s, unsigned short* __restrict__ d) {
  int i = (blockIdx.x * 256 + threadIdx.x) * 4;
  f32x4 f = *(const f32x4*)(s + i);
  u16x4 o = { f2bf(f[0]), f2bf(f[1]), f2bf(f[2]), f2bf(f[3]) };
  *(u16x4*)(d + i) = o;
}

__global__ void cvt_w(const float* __restrict__ w0, const float* __restrict__ w1,
                      const float* __restrict__ w2, const float* __restrict__ w3,
                      unsigned short* __restrict__ dst) {
  const float* s = blockIdx.z == 0 ? w0 : blockIdx.z == 1 ? w1 : blockIdx.z == 2 ? w2 : w3;
  unsigned short* d = dst + (size_t)blockIdx.z * 1048576;
  int i = (blockIdx.x * 256 + threadIdx.x) * 4;
  f32x4 f = *(const f32x4*)(s + i);
  u16x4 o = { f2bf(f[0]), f2bf(f[1]), f2bf(f[2]), f2bf(f[3]) };
  *(u16x4*)(d + i) = o;
}

// ---------------- NT bf16 GEMM, 128x128 tile, BK=64, 2-phase dbuf ----------
// C[m][n] = sum_k A[m][k]*W[n][k] + bias[n]
// MODE 0: z selects {wq,wk,wv}; Q,K -> head-major [z][b][h][s][d] bf16;
//         V (z==2) -> TRANSPOSED [b][h][d][s] bf16 (for attention B-frags)
// MODE 1: single weight; writes fp32 row-major (d_out)
template <int MODE>
__global__ __launch_bounds__(256)
void gemm_bt(const unsigned short* __restrict__ A,
             const unsigned short* __restrict__ Wbase,
             const float* __restrict__ b0, const float* __restrict__ b1,
             const float* __restrict__ b2,
             unsigned short* __restrict__ obf, float* __restrict__ of32) {
  const int K = 1024;
  const int z = blockIdx.z;
  const unsigned short* W = Wbase + (size_t)z * 1048576;
  const float* bias = (z == 0) ? b0 : (z == 1) ? b1 : b2;

  // XCD-aware bijective swizzle of (x,y): nwg = 8*32 = 256, divisible by 8.
  int flat = blockIdx.y * 8 + blockIdx.x;
  int swz = (flat & 7) * 32 + (flat >> 3);
  const int n0 = (swz & 7) * 128, m0 = (swz >> 3) * 128;

  const int tid = threadIdx.x, lane = tid & 63, w = tid >> 6;
  const int wr = w >> 1, wc = w & 1;
  const int fr = lane & 15, g = lane >> 4;

  __shared__ unsigned short lA[2][128 * 64];
  __shared__ unsigned short lB[2][128 * 64];

  f32x4 acc[4][4] = {};

#define STAGE(d, t)                                                              \
  _Pragma("unroll") for (int i = 0; i < 4; ++i) {                                \
    int s = i * 256 + tid;                                                       \
    gload_lds16(A + (size_t)(m0 + (s >> 3)) * K + (t)*64 + (s & 7) * 8,          \
                &lA[d][s * 8]);                                                  \
    gload_lds16(W + (size_t)(n0 + (s >> 3)) * K + (t)*64 + (s & 7) * 8,          \
                &lB[d][s * 8]);                                                  \
  }

#define COMPUTE(d)                                                               \
  _Pragma("unroll") for (int kk = 0; kk < 2; ++kk) {                             \
    short8 af[4], bfr[4];                                                        \
    _Pragma("unroll") for (int m = 0; m < 4; ++m)                                \
        af[m] = *(const short8*)&lA[d][(wr * 64 + m * 16 + fr) * 64 + kk * 32 +  \
                                       g * 8];                                   \
    _Pragma("unroll") for (int n = 0; n < 4; ++n)                                \
        bfr[n] = *(const short8*)&lB[d][(wc * 64 + n * 16 + fr) * 64 + kk * 32 + \
                                        g * 8];                                  \
    _Pragma("unroll") for (int m = 0; m < 4; ++m)                                \
        _Pragma("unroll") for (int n = 0; n < 4; ++n)                            \
        acc[m][n] =                                                              \
            __builtin_amdgcn_mfma_f32_16x16x32_bf16(af[m], bfr[n], acc[m][n],    \
                                                    0, 0, 0);                    \
  }

  STAGE(0, 0);
  __syncthreads();
  int cur = 0;
  for (int t = 0; t < 15; ++t) {
    STAGE(cur ^ 1, t + 1);   // next tile's loads in flight during compute
    __builtin_amdgcn_s_setprio(1);
    COMPUTE(cur);
    __builtin_amdgcn_s_setprio(0);
    __syncthreads();         // drains vmcnt -> staged buffer ready
    cur ^= 1;
  }
  COMPUTE(cur);
#undef STAGE
#undef COMPUTE

  const int rb = g * 4, cl = fr;
#pragma unroll
  for (int m = 0; m < 4; ++m) {
#pragma unroll
    for (int n = 0; n < 4; ++n) {
      int col = n0 + wc * 64 + n * 16 + cl;
      float bias_v = bias[col];
      int row0 = m0 + wr * 64 + m * 16 + rb;
      if (MODE == 0) {
        int hh = col >> 6, d = col & 63;
        int bb = row0 >> 11, s0 = row0 & 2047;
        if (z == 2) {
          u16x4 pk;
#pragma unroll
          for (int i = 0; i < 4; ++i) pk[i] = f2bf(acc[m][n][i] + bias_v);
          *(u16x4*)&obf[(((size_t)(64 + bb * 16 + hh)) * 64 + d) * 2048 + s0] = pk;
        } else {
#pragma unroll
          for (int i = 0; i < 4; ++i)
            obf[(((size_t)(z * 32 + bb * 16 + hh)) * 2048 + s0 + i) * 64 + d] =
                f2bf(acc[m][n][i] + bias_v);
        }
      } else {
#pragma unroll
        for (int i = 0; i < 4; ++i)
          of32[(size_t)(row0 + i) * 1024 + col] = acc[m][n][i] + bias_v;
      }
    }
  }
}

// ---------------- MFMA flash attention, window=256 ----------------
__global__ __launch_bounds__(256)
void attn_mfma(const unsigned short* __restrict__ QKV, unsigned short* __restrict__ AO) {
  const int S = 2048;
  const int b = blockIdx.z, h = blockIdx.y;
  const int q0 = blockIdx.x * 128;
  const size_t hb = (size_t)(b * 16 + h);
  const unsigned short* Qh = QKV + hb * (S * 64);
  const unsigned short* Kh = QKV + 4194304 + hb * (S * 64);
  const unsigned short* Vt = QKV + 8388608 + hb * (S * 64);  // [64][2048]

  const int tid = threadIdx.x;
  const int lane = tid & 63, w = tid >> 6;
  const int c = lane & 15, g = lane >> 4;
  const int qw0 = q0 + 32 * w;

  __shared__ unsigned short Plds[4][1024];
  char* Pb = (char*)&Plds[w][0];

  short8 qa[2][2];
#pragma unroll
  for (int mi = 0; mi < 2; ++mi)
#pragma unroll
    for (int cs = 0; cs < 2; ++cs)
      qa[mi][cs] = *(const short8*)(Qh + (size_t)(qw0 + 16 * mi + c) * 64 + 32 * cs + g * 8);

  f32x4 o[2][4] = {};
  float mrow[2][4], lsum[2][4];
#pragma unroll
  for (int mi = 0; mi < 2; ++mi)
#pragma unroll
    for (int r = 0; r < 4; ++r) { mrow[mi][r] = -1e30f; lsum[mi][r] = 0.f; }

  int kt0 = qw0 - 256; if (kt0 < 0) kt0 = 0;
  const int ktlast = qw0;

  short8 kf[2][2], vf[4];
#pragma unroll
  for (int ni = 0; ni < 2; ++ni)
#pragma unroll
    for (int cs = 0; cs < 2; ++cs)
      kf[ni][cs] = *(const short8*)(Kh + (size_t)(kt0 + 16 * ni + c) * 64 + 32 * cs + g * 8);
#pragma unroll
  for (int ni = 0; ni < 4; ++ni)
    vf[ni] = *(const short8*)(Vt + (size_t)(16 * ni + c) * 2048 + kt0 + g * 8);

  for (int kt = kt0; kt <= ktlast; kt += 32) {
    const int ktn = (kt + 32 <= ktlast) ? kt + 32 : kt;
    short8 kfn[2][2], vfn[4];
#pragma unroll
    for (int ni = 0; ni < 2; ++ni)
#pragma unroll
      for (int cs = 0; cs < 2; ++cs)
        kfn[ni][cs] = *(const short8*)(Kh + (size_t)(ktn + 16 * ni + c) * 64 + 32 * cs + g * 8);
#pragma unroll
    for (int ni = 0; ni < 4; ++ni)
      vfn[ni] = *(const short8*)(Vt + (size_t)(16 * ni + c) * 2048 + ktn + g * 8);

    f32x4 sA[2][2] = {};
#pragma unroll
    for (int mi = 0; mi < 2; ++mi)
#pragma unroll
      for (int ni = 0; ni < 2; ++ni)
#pragma unroll
        for (int cs = 0; cs < 2; ++cs)
          sA[mi][ni] = __builtin_amdgcn_mfma_f32_16x16x32_bf16(qa[mi][cs], kf[ni][cs],
                                                               sA[mi][ni], 0, 0, 0);

    float sv[2][2][4];
#pragma unroll
    for (int mi = 0; mi < 2; ++mi)
#pragma unroll
      for (int ni = 0; ni < 2; ++ni)
#pragma unroll
        for (int r = 0; r < 4; ++r) {
          int q = qw0 + 16 * mi + 4 * g + r;
          int k = kt + 16 * ni + c;
          sv[mi][ni][r] = ((unsigned)(q - k) <= 256u) ? sA[mi][ni][r] * 0.125f : -3.0e38f;
        }

#pragma unroll
    for (int mi = 0; mi < 2; ++mi) {
#pragma unroll
      for (int r = 0; r < 4; ++r) {
        float tm = fmaxf(sv[mi][0][r], sv[mi][1][r]);
        tm = fmaxf(tm, __shfl_xor(tm, 1));
        tm = fmaxf(tm, __shfl_xor(tm, 2));
        tm = fmaxf(tm, __shfl_xor(tm, 4));
        tm = fmaxf(tm, __shfl_xor(tm, 8));
        float mnew = fmaxf(mrow[mi][r], tm);
        float sc = __expf(mrow[mi][r] - mnew);
        mrow[mi][r] = mnew;
        float p0 = __expf(sv[mi][0][r] - mnew);
        float p1 = __expf(sv[mi][1][r] - mnew);
        float ps = p0 + p1;
        ps += __shfl_xor(ps, 1);
        ps += __shfl_xor(ps, 2);
        ps += __shfl_xor(ps, 4);
        ps += __shfl_xor(ps, 8);
        lsum[mi][r] = lsum[mi][r] * sc + ps;
#pragma unroll
        for (int ni = 0; ni < 4; ++ni)
          o[mi][ni][r] *= sc;
        int qloc = 16 * mi + 4 * g + r;
        int xr = (qloc & 12) << 2;
        *(unsigned short*)(Pb + ((qloc * 64 + c * 2) ^ xr)) = f2bf(p0);
        *(unsigned short*)(Pb + ((qloc * 64 + 32 + c * 2) ^ xr)) = f2bf(p1);
      }
    }

#pragma unroll
    for (int mi = 0; mi < 2; ++mi) {
      int qloc = 16 * mi + c;
      short8 pa = *(const short8*)(Pb + ((qloc * 64 + g * 16) ^ ((qloc & 12) << 2)));
#pragma unroll
      for (int ni = 0; ni < 4; ++ni)
        o[mi][ni] = __builtin_amdgcn_mfma_f32_16x16x32_bf16(pa, vf[ni], o[mi][ni], 0, 0, 0);
    }

#pragma unroll
    for (int ni = 0; ni < 2; ++ni)
#pragma unroll
      for (int cs = 0; cs < 2; ++cs)
        kf[ni][cs] = kfn[ni][cs];
#pragma unroll
    for (int ni = 0; ni < 4; ++ni)
      vf[ni] = vfn[ni];
  }

#pragma unroll
  for (int mi = 0; mi < 2; ++mi)
#pragma unroll
    for (int r = 0; r < 4; ++r) {
      float inv = 1.f / lsum[mi][r];
      int q = qw0 + 16 * mi + 4 * g + r;
      unsigned short* row = AO + (size_t)(b * 2048 + q) * 1024 + h * 64 + c;
#pragma unroll
      for (int ni = 0; ni < 4; ++ni)
        row[16 * ni] = f2bf(o[mi][ni][r] * inv);
    }
}

extern "C" void kernel_launch(void* const* d_in, const int* in_sizes, int n_in,
                              void* d_out, int out_size, void* d_ws, size_t ws_size,
                              hipStream_t stream) {
  const float* X  = (const float*)d_in[0];
  const float* wq = (const float*)d_in[1];
  const float* bq = (const float*)d_in[2];
  const float* wk = (const float*)d_in[3];
  const float* bk = (const float*)d_in[4];
  const float* wv = (const float*)d_in[5];
  const float* bv = (const float*)d_in[6];
  const float* wo = (const float*)d_in[7];
  const float* bo = (const float*)d_in[8];
  float* out = (float*)d_out;

  // workspace (ushort elems): Xb[4194304] | Wb[4x1048576] | QKV[3x4194304] | AO[4194304]
  unsigned short* Xb  = (unsigned short*)d_ws;
  unsigned short* Wb  = Xb + 4194304;
  unsigned short* QKV = Wb + 4194304;
  unsigned short* AO  = QKV + 12582912;

  cvt4<<<dim3(4096), dim3(256), 0, stream>>>(X, Xb);
  cvt_w<<<dim3(1024, 1, 4), dim3(256), 0, stream>>>(wq, wk, wv, wo, Wb);
  gemm_bt<0><<<dim3(8, 32, 3), dim3(256), 0, stream>>>(Xb, Wb, bq, bk, bv, QKV, nullptr);
  attn_mfma<<<dim3(16, 16, 2), dim3(256), 0, stream>>>(QKV, AO);
  gemm_bt<1><<<dim3(8, 32, 1), dim3(256), 0, stream>>>(AO, Wb + 3 * 1048576, bo, bo, bo, nullptr, out);
}

// Round 4
// 92.938 us; speedup vs baseline: 1.2724x; 1.2724x over previous
//
#include <hip/hip_runtime.h>
#include <hip/hip_bf16.h>
#include <stdint.h>

typedef __attribute__((ext_vector_type(8))) short short8;
typedef __attribute__((ext_vector_type(4))) float f32x4;
typedef __attribute__((ext_vector_type(4))) unsigned short u16x4;

__device__ __forceinline__ float bf2f(unsigned short u) {
  union { unsigned int u; float f; } x; x.u = ((unsigned int)u) << 16; return x.f;
}
__device__ __forceinline__ unsigned short f2bf(float f) {
  union { float f; unsigned int u; } x; x.f = f;
  unsigned int u = x.u;
  return (unsigned short)((u + 0x7fffu + ((u >> 16) & 1u)) >> 16);
}

__device__ __forceinline__ void gload_lds16(const void* g, void* l) {
  __builtin_amdgcn_global_load_lds(
      (const __attribute__((address_space(1))) void*)g,
      (__attribute__((address_space(3))) void*)l, 16, 0, 0);
}

// ---------------- fp32 -> bf16 converts ----------------
__global__ void cvt4(const float* __restrict__ s, unsigned short* __restrict__ d) {
  int i = (blockIdx.x * 256 + threadIdx.x) * 4;
  f32x4 f = *(const f32x4*)(s + i);
  u16x4 o = { f2bf(f[0]), f2bf(f[1]), f2bf(f[2]), f2bf(f[3]) };
  *(u16x4*)(d + i) = o;
}

__global__ void cvt_w(const float* __restrict__ w0, const float* __restrict__ w1,
                      const float* __restrict__ w2, const float* __restrict__ w3,
                      unsigned short* __restrict__ dst) {
  const float* s = blockIdx.z == 0 ? w0 : blockIdx.z == 1 ? w1 : blockIdx.z == 2 ? w2 : w3;
  unsigned short* d = dst + (size_t)blockIdx.z * 1048576;
  int i = (blockIdx.x * 256 + threadIdx.x) * 4;
  f32x4 f = *(const f32x4*)(s + i);
  u16x4 o = { f2bf(f[0]), f2bf(f[1]), f2bf(f[2]), f2bf(f[3]) };
  *(u16x4*)(d + i) = o;
}

// ---------------- NT bf16 GEMM, 128x128 tile, BK=32, triple-buffer ring ----
// Counted-vmcnt pipeline: stage tile t+2 during compute of tile t.
//   per iter: vmcnt(4) [tile t complete, t+1 in flight] -> raw s_barrier
//             -> stage t+2 -> 16 MFMA.
// LDS chunk swizzle (both-sides, rule 21): global source chunk and ds_read
// chunk both XOR'd with (row>>1)&3 -> 2-way bank conflict (free).
// MODE 0: z selects {wq,wk,wv}; Q,K -> head-major [z][b][h][s][d] bf16;
//         V (z==2) -> TRANSPOSED [b][h][d][s] bf16 (for attention B-frags)
// MODE 1: single weight; writes fp32 row-major (d_out)
template <int MODE>
__global__ __launch_bounds__(256)
void gemm_bt(const unsigned short* __restrict__ A,
             const unsigned short* __restrict__ Wbase,
             const float* __restrict__ b0, const float* __restrict__ b1,
             const float* __restrict__ b2,
             unsigned short* __restrict__ obf, float* __restrict__ of32) {
  const int K = 1024, NT = 32;
  const int z = blockIdx.z;
  const unsigned short* W = Wbase + (size_t)z * 1048576;
  const float* bias = (z == 0) ? b0 : (z == 1) ? b1 : b2;

  // XCD-aware bijective swizzle: nwg = 256 per z, divisible by 8.
  int flat = blockIdx.y * 8 + blockIdx.x;
  int swz = (flat & 7) * 32 + (flat >> 3);
  const int n0 = (swz & 7) * 128, m0 = (swz >> 3) * 128;

  const int tid = threadIdx.x, lane = tid & 63, w = tid >> 6;
  const int wr = w >> 1, wc = w & 1;
  const int fr = lane & 15, g = lane >> 4;

  // [3 ring bufs][A: 0..4095 | B: 4096..8191] ushorts (16 KB per buf)
  __shared__ unsigned short lds[3][8192];

  f32x4 acc[4][4] = {};

#define STAGE(bi, t)                                                            \
  do {                                                                          \
    _Pragma("unroll") for (int i = 0; i < 2; ++i) {                             \
      int s = i * 256 + tid;                                                    \
      int row = s >> 2;                                                         \
      int gc = (s & 3) ^ ((row >> 1) & 3);                                      \
      gload_lds16(A + (size_t)(m0 + row) * K + (t) * 32 + gc * 8,               \
                  &lds[bi][s * 8]);                                             \
      gload_lds16(W + (size_t)(n0 + row) * K + (t) * 32 + gc * 8,               \
                  &lds[bi][4096 + s * 8]);                                      \
    }                                                                           \
  } while (0)

#define COMPUTE(bi)                                                             \
  do {                                                                          \
    short8 af[4], bfr[4];                                                       \
    _Pragma("unroll") for (int m = 0; m < 4; ++m) {                             \
      int ra = wr * 64 + m * 16 + fr;                                           \
      af[m] = *(const short8*)&lds[bi][ra * 32 + ((g ^ ((ra >> 1) & 3)) * 8)];  \
    }                                                                           \
    _Pragma("unroll") for (int n = 0; n < 4; ++n) {                             \
      int rb2 = wc * 64 + n * 16 + fr;                                          \
      bfr[n] =                                                                  \
          *(const short8*)&lds[bi][4096 + rb2 * 32 + ((g ^ ((rb2 >> 1) & 3)) * 8)]; \
    }                                                                           \
    _Pragma("unroll") for (int m = 0; m < 4; ++m)                               \
        _Pragma("unroll") for (int n = 0; n < 4; ++n)                           \
        acc[m][n] = __builtin_amdgcn_mfma_f32_16x16x32_bf16(af[m], bfr[n],      \
                                                            acc[m][n], 0, 0, 0);\
  } while (0)

  STAGE(0, 0);
  STAGE(1, 1);
  for (int t = 0; t < NT; ++t) {
    // tile t's loads must be complete in EVERY wave before ANY wave reads:
    // per-wave counted wait, then barrier.
    if (t < NT - 1)
      asm volatile("s_waitcnt vmcnt(4)" ::: "memory");  // t+1's 4 loads may fly
    else
      asm volatile("s_waitcnt vmcnt(0)" ::: "memory");
    __builtin_amdgcn_s_barrier();
    __builtin_amdgcn_sched_barrier(0);
    // stage t+2 into buf[(t+2)%3]: nobody reads it (waves are within 1 tile).
    if (t + 2 < NT) STAGE((t + 2) % 3, t + 2);
    __builtin_amdgcn_s_setprio(1);
    COMPUTE(t % 3);
    __builtin_amdgcn_s_setprio(0);
  }
#undef STAGE
#undef COMPUTE

  const int rb = g * 4, cl = fr;
#pragma unroll
  for (int m = 0; m < 4; ++m) {
#pragma unroll
    for (int n = 0; n < 4; ++n) {
      int col = n0 + wc * 64 + n * 16 + cl;
      float bias_v = bias[col];
      int row0 = m0 + wr * 64 + m * 16 + rb;
      if (MODE == 0) {
        int hh = col >> 6, d = col & 63;
        int bb = row0 >> 11, s0 = row0 & 2047;
        if (z == 2) {
          u16x4 pk;
#pragma unroll
          for (int i = 0; i < 4; ++i) pk[i] = f2bf(acc[m][n][i] + bias_v);
          *(u16x4*)&obf[(((size_t)(64 + bb * 16 + hh)) * 64 + d) * 2048 + s0] = pk;
        } else {
#pragma unroll
          for (int i = 0; i < 4; ++i)
            obf[(((size_t)(z * 32 + bb * 16 + hh)) * 2048 + s0 + i) * 64 + d] =
                f2bf(acc[m][n][i] + bias_v);
        }
      } else {
#pragma unroll
        for (int i = 0; i < 4; ++i)
          of32[(size_t)(row0 + i) * 1024 + col] = acc[m][n][i] + bias_v;
      }
    }
  }
}

// ---------------- MFMA flash attention, window=256 ----------------
__global__ __launch_bounds__(256)
void attn_mfma(const unsigned short* __restrict__ QKV, unsigned short* __restrict__ AO) {
  const int S = 2048;
  const int b = blockIdx.z, h = blockIdx.y;
  const int q0 = blockIdx.x * 128;
  const size_t hb = (size_t)(b * 16 + h);
  const unsigned short* Qh = QKV + hb * (S * 64);
  const unsigned short* Kh = QKV + 4194304 + hb * (S * 64);
  const unsigned short* Vt = QKV + 8388608 + hb * (S * 64);  // [64][2048]

  const int tid = threadIdx.x;
  const int lane = tid & 63, w = tid >> 6;
  const int c = lane & 15, g = lane >> 4;
  const int qw0 = q0 + 32 * w;

  __shared__ unsigned short Plds[4][1024];
  char* Pb = (char*)&Plds[w][0];

  short8 qa[2][2];
#pragma unroll
  for (int mi = 0; mi < 2; ++mi)
#pragma unroll
    for (int cs = 0; cs < 2; ++cs)
      qa[mi][cs] = *(const short8*)(Qh + (size_t)(qw0 + 16 * mi + c) * 64 + 32 * cs + g * 8);

  f32x4 o[2][4] = {};
  float mrow[2][4], lsum[2][4];
#pragma unroll
  for (int mi = 0; mi < 2; ++mi)
#pragma unroll
    for (int r = 0; r < 4; ++r) { mrow[mi][r] = -1e30f; lsum[mi][r] = 0.f; }

  int kt0 = qw0 - 256; if (kt0 < 0) kt0 = 0;
  const int ktlast = qw0;

  short8 kf[2][2], vf[4];
#pragma unroll
  for (int ni = 0; ni < 2; ++ni)
#pragma unroll
    for (int cs = 0; cs < 2; ++cs)
      kf[ni][cs] = *(const short8*)(Kh + (size_t)(kt0 + 16 * ni + c) * 64 + 32 * cs + g * 8);
#pragma unroll
  for (int ni = 0; ni < 4; ++ni)
    vf[ni] = *(const short8*)(Vt + (size_t)(16 * ni + c) * 2048 + kt0 + g * 8);

  for (int kt = kt0; kt <= ktlast; kt += 32) {
    const int ktn = (kt + 32 <= ktlast) ? kt + 32 : kt;
    short8 kfn[2][2], vfn[4];
#pragma unroll
    for (int ni = 0; ni < 2; ++ni)
#pragma unroll
      for (int cs = 0; cs < 2; ++cs)
        kfn[ni][cs] = *(const short8*)(Kh + (size_t)(ktn + 16 * ni + c) * 64 + 32 * cs + g * 8);
#pragma unroll
    for (int ni = 0; ni < 4; ++ni)
      vfn[ni] = *(const short8*)(Vt + (size_t)(16 * ni + c) * 2048 + ktn + g * 8);

    f32x4 sA[2][2] = {};
#pragma unroll
    for (int mi = 0; mi < 2; ++mi)
#pragma unroll
      for (int ni = 0; ni < 2; ++ni)
#pragma unroll
        for (int cs = 0; cs < 2; ++cs)
          sA[mi][ni] = __builtin_amdgcn_mfma_f32_16x16x32_bf16(qa[mi][cs], kf[ni][cs],
                                                               sA[mi][ni], 0, 0, 0);

    float sv[2][2][4];
#pragma unroll
    for (int mi = 0; mi < 2; ++mi)
#pragma unroll
      for (int ni = 0; ni < 2; ++ni)
#pragma unroll
        for (int r = 0; r < 4; ++r) {
          int q = qw0 + 16 * mi + 4 * g + r;
          int k = kt + 16 * ni + c;
          sv[mi][ni][r] = ((unsigned)(q - k) <= 256u) ? sA[mi][ni][r] * 0.125f : -3.0e38f;
        }

#pragma unroll
    for (int mi = 0; mi < 2; ++mi) {
#pragma unroll
      for (int r = 0; r < 4; ++r) {
        float tm = fmaxf(sv[mi][0][r], sv[mi][1][r]);
        tm = fmaxf(tm, __shfl_xor(tm, 1));
        tm = fmaxf(tm, __shfl_xor(tm, 2));
        tm = fmaxf(tm, __shfl_xor(tm, 4));
        tm = fmaxf(tm, __shfl_xor(tm, 8));
        float mnew = fmaxf(mrow[mi][r], tm);
        float sc = __expf(mrow[mi][r] - mnew);
        mrow[mi][r] = mnew;
        float p0 = __expf(sv[mi][0][r] - mnew);
        float p1 = __expf(sv[mi][1][r] - mnew);
        float ps = p0 + p1;
        ps += __shfl_xor(ps, 1);
        ps += __shfl_xor(ps, 2);
        ps += __shfl_xor(ps, 4);
        ps += __shfl_xor(ps, 8);
        lsum[mi][r] = lsum[mi][r] * sc + ps;
#pragma unroll
        for (int ni = 0; ni < 4; ++ni)
          o[mi][ni][r] *= sc;
        int qloc = 16 * mi + 4 * g + r;
        int xr = (qloc & 12) << 2;
        *(unsigned short*)(Pb + ((qloc * 64 + c * 2) ^ xr)) = f2bf(p0);
        *(unsigned short*)(Pb + ((qloc * 64 + 32 + c * 2) ^ xr)) = f2bf(p1);
      }
    }

#pragma unroll
    for (int mi = 0; mi < 2; ++mi) {
      int qloc = 16 * mi + c;
      short8 pa = *(const short8*)(Pb + ((qloc * 64 + g * 16) ^ ((qloc & 12) << 2)));
#pragma unroll
      for (int ni = 0; ni < 4; ++ni)
        o[mi][ni] = __builtin_amdgcn_mfma_f32_16x16x32_bf16(pa, vf[ni], o[mi][ni], 0, 0, 0);
    }

#pragma unroll
    for (int ni = 0; ni < 2; ++ni)
#pragma unroll
      for (int cs = 0; cs < 2; ++cs)
        kf[ni][cs] = kfn[ni][cs];
#pragma unroll
    for (int ni = 0; ni < 4; ++ni)
      vf[ni] = vfn[ni];
  }

#pragma unroll
  for (int mi = 0; mi < 2; ++mi)
#pragma unroll
    for (int r = 0; r < 4; ++r) {
      float inv = 1.f / lsum[mi][r];
      int q = qw0 + 16 * mi + 4 * g + r;
      unsigned short* row = AO + (size_t)(b * 2048 + q) * 1024 + h * 64 + c;
#pragma unroll
      for (int ni = 0; ni < 4; ++ni)
        row[16 * ni] = f2bf(o[mi][ni][r] * inv);
    }
}

extern "C" void kernel_launch(void* const* d_in, const int* in_sizes, int n_in,
                              void* d_out, int out_size, void* d_ws, size_t ws_size,
                              hipStream_t stream) {
  const float* X  = (const float*)d_in[0];
  const float* wq = (const float*)d_in[1];
  const float* bq = (const float*)d_in[2];
  const float* wk = (const float*)d_in[3];
  const float* bk = (const float*)d_in[4];
  const float* wv = (const float*)d_in[5];
  const float* bv = (const float*)d_in[6];
  const float* wo = (const float*)d_in[7];
  const float* bo = (const float*)d_in[8];
  float* out = (float*)d_out;

  // workspace (ushort elems): Xb[4194304] | Wb[4x1048576] | QKV[3x4194304] | AO[4194304]
  unsigned short* Xb  = (unsigned short*)d_ws;
  unsigned short* Wb  = Xb + 4194304;
  unsigned short* QKV = Wb + 4194304;
  unsigned short* AO  = QKV + 12582912;

  cvt4<<<dim3(4096), dim3(256), 0, stream>>>(X, Xb);
  cvt_w<<<dim3(1024, 1, 4), dim3(256), 0, stream>>>(wq, wk, wv, wo, Wb);
  gemm_bt<0><<<dim3(8, 32, 3), dim3(256), 0, stream>>>(Xb, Wb, bq, bk, bv, QKV, nullptr);
  attn_mfma<<<dim3(16, 16, 2), dim3(256), 0, stream>>>(QKV, AO);
  gemm_bt<1><<<dim3(8, 32, 1), dim3(256), 0, stream>>>(AO, Wb + 3 * 1048576, bo, bo, bo, nullptr, out);
}